// Round 4
// baseline (231.983 us; speedup 1.0000x reference)
//
#include <hip/hip_runtime.h>
#include <math.h>

// SSIM fused single pass, v9.
// History: v5 = 67.2us/disp, VALUBusy 52%, HBM 12%, 0 conflicts, VGPR 80.
//   v6 (pipelined staging) NEUTRAL: LDS/vmcnt roundtrip wasn't the stall.
//   v7 (TY=23, 1104 blocks) REGRESSED 86us: 1104 = 4x256+80 -> 80 CUs carry
//     5 blocks; dispatch waits on the stragglers (+25% predicted, +27% seen).
//   v8 FAILED (aborted): PHASE_BODY macro param shadowed the caller's P ->
//     `const int P = (P);` self-init UB -> indeterminate slot indices.
//     The occupancy experiment never ran.
// v9 = v8's experiment with the macro DELETED (v5-proven body inline):
//  * single fully-unrolled j = 0..25 loop; P = j%11 const-folds since j is
//    a literal under full unroll. Identical math to v5/v7.
//  * TY=16 -> grid (32,48) = 1536 blocks = EXACTLY 6 blocks/CU (192/XCD),
//    perfectly balanced; 24 waves/CU = 6 waves/SIMD = VGPR-80 residency cap
//    (6x80=480<=512; LDS 9216B allows 17 blocks). 2x v5's latency hiding.
//  * no launch_bounds min-waves hint: natural VGPR=80 already fits 6/SIMD.
//  * Halo tax: phase-work/CU 6x26=156 vs v5's 3x44=132 (+18%), repaid if
//    the 48% stall fraction shrinks (VALU-cycle model: ~35us issue floor).

#define KW 11
#define RAD 5
#define IMG_W 512
#define IMG_H 512
#define TY 16                // output rows per tile
#define NPH (TY + 2 * RAD)   // 26 phases
#define NV4 70               // 140 staged (a,b) pairs = 70 v4f per row buffer
#define C1F 0.0001f          // 0.01^2
#define C2F 0.0009f          // 0.03^2

typedef float v2f __attribute__((ext_vector_type(2)));
typedef float v4f __attribute__((ext_vector_type(4)));

struct GaussW { float g[KW]; };

__global__ __launch_bounds__(256) void ssim_fused_kernel(
    const float* __restrict__ img1,
    const float* __restrict__ img2,
    float* __restrict__ out,
    float inv_n,
    GaussW gw)
{
    __shared__ v4f rows[4][2][NV4];   // [wave][double-buffer][v4f = 2 (a,b) pairs]
    __shared__ float red[4];

    const int tid  = threadIdx.x;
    const int lane = tid & 63;
    const int wvi  = tid >> 6;

    const int x0 = wvi * 128;              // wave's 128-col strip
    const int y0 = blockIdx.x * TY;        // wave's first output row

    const size_t pbase = (size_t)blockIdx.y * (size_t)(IMG_W * IMG_H);
    const float* __restrict__ p1 = img1 + pbase;
    const float* __restrict__ p2 = img2 + pbase;

    // Gaussian weights: by-value kernarg -> SGPRs (wave-uniform).
    float g[KW];
    #pragma unroll
    for (int i = 0; i < KW; ++i) g[i] = gw.g[i];

    // Staged entries cover cols x0-6 .. x0+133 (140 entries, even start for
    // aligned float2 loads). Lane t owns entries {2t, 2t+1}; lanes 0..5 also
    // stage halo entries {128+2l, 129+2l}.
    const int cm  = x0 - 6 + 2 * lane;                 // main col (even)
    const int cmc = min(max(cm, 0), IMG_W - 2);        // clamped, even
    const float mm0 = (cm     >= 0 && cm     < IMG_W) ? 1.f : 0.f;
    const float mm1 = (cm + 1 >= 0 && cm + 1 < IMG_W) ? 1.f : 0.f;
    const int ch  = x0 + 122 + 2 * lane;               // halo col (lanes 0..5)
    const int chc = min(max(ch, 0), IMG_W - 2);
    const float mh0 = (ch     < IMG_W) ? 1.f : 0.f;
    const float mh1 = (ch + 1 < IMG_W) ? 1.f : 0.f;

    // Load row (y0-RAD+j) into interleaved+masked (a0,b0,a1,b1) v4f regs.
    auto load_row = [&](int j, v4f& vm, v4f& vh) {
        const int ir = y0 - RAD + j;
        vm = (v4f){0.f, 0.f, 0.f, 0.f};
        vh = (v4f){0.f, 0.f, 0.f, 0.f};
        if ((unsigned)ir < (unsigned)IMG_H) {   // wave-uniform branch
            const float* r1 = p1 + ir * IMG_W;
            const float* r2 = p2 + ir * IMG_W;
            const v2f a = *reinterpret_cast<const v2f*>(r1 + cmc);
            const v2f b = *reinterpret_cast<const v2f*>(r2 + cmc);
            vm = (v4f){a.x * mm0, b.x * mm0, a.y * mm1, b.y * mm1};
            if (lane < 6) {
                const v2f ah = *reinterpret_cast<const v2f*>(r1 + chc);
                const v2f bh = *reinterpret_cast<const v2f*>(r2 + chc);
                vh = (v4f){ah.x * mh0, bh.x * mh0, ah.y * mh1, bh.y * mh1};
            }
        }
    };

    // V scatter accumulators for the thread's 2 columns (A=2lane, B=2lane+1):
    // slot s holds output row m with m%11==s.  (mu1,mu2) and (S,P) per px.
    v2f aMuA[KW], aSPA[KW], aMuB[KW], aSPB[KW];
    #pragma unroll
    for (int s = 0; s < KW; ++s) {
        aMuA[s] = (v2f){0.f, 0.f}; aSPA[s] = (v2f){0.f, 0.f};
        aMuB[s] = (v2f){0.f, 0.f}; aSPB[s] = (v2f){0.f, 0.f};
    }

    v4f curm, curh;
    load_row(0, curm, curh);

    float acc = 0.f;

    // Single fully-unrolled phase loop; j literal => P = j%11 const-folds.
    #pragma unroll
    for (int j = 0; j < NPH; ++j) {
        const int P   = j % KW;
        const int buf = j & 1;
        v4f* __restrict__ wrow = rows[wvi][buf];

        // ---- stage row j (regs -> wave-private LDS) ----
        wrow[lane] = curm;                          // ds_write_b128
        if (lane < 6) wrow[64 + lane] = curh;
        __threadfence_block();   // wave-local lgkmcnt drain; orders W_j < R_j
                                 // and (via F_{j+1}) R_j < W_{j+2}

        // ---- prefetch row j+1 (latency covered by this iter's math) ----
        if (j < NPH - 1) load_row(j + 1, curm, curh);

        // ---- read the 14-pair window: v4f slots lane..lane+6 ----
        v4f e[7];
        #pragma unroll
        for (int r = 0; r < 7; ++r) e[r] = wrow[lane + r];   // ds_read_b128

        // pairs: idx 0..13; pair(i) = i even ? e[i/2].xy : e[i/2].zw
        // window for col A uses pairs 1..11, col B uses pairs 2..12.
        v2f ab[14], sp[14];
        #pragma unroll
        for (int i = 0; i < 14; ++i) {
            const v4f q = e[i >> 1];
            const v2f t = (i & 1) ? (v2f){q.z, q.w} : (v2f){q.x, q.y};
            ab[i] = t;
        }
        #pragma unroll
        for (int i = 1; i <= 12; ++i) {
            const v2f t = ab[i];
            sp[i] = (v2f){fmaf(t.x, t.x, t.y * t.y), t.x * t.y};
        }

        // ---- horizontal 11-tap conv, 2 px, packed ----
        v2f hMuA = (v2f){0.f, 0.f}, hSPA = (v2f){0.f, 0.f};
        v2f hMuB = (v2f){0.f, 0.f}, hSPB = (v2f){0.f, 0.f};
        #pragma unroll
        for (int k = 0; k < KW; ++k) {
            const v2f gk = (v2f){g[k], g[k]};
            hMuA = __builtin_elementwise_fma(gk, ab[1 + k], hMuA);
            hSPA = __builtin_elementwise_fma(gk, sp[1 + k], hSPA);
            hMuB = __builtin_elementwise_fma(gk, ab[2 + k], hMuB);
            hSPB = __builtin_elementwise_fma(gk, sp[2 + k], hSPB);
        }

        // ---- vertical scatter; slot s==P gets its FIRST tap: assign ----
        #pragma unroll
        for (int s = 0; s < KW; ++s) {
            const float wt = g[(P - s + KW) % KW];
            const v2f wv2 = (v2f){wt, wt};
            if (s == P) {
                aMuA[s] = wv2 * hMuA;  aSPA[s] = wv2 * hSPA;
                aMuB[s] = wv2 * hMuB;  aSPB[s] = wv2 * hSPB;
            } else {
                aMuA[s] = __builtin_elementwise_fma(wv2, hMuA, aMuA[s]);
                aSPA[s] = __builtin_elementwise_fma(wv2, hSPA, aSPA[s]);
                aMuB[s] = __builtin_elementwise_fma(wv2, hMuB, aMuB[s]);
                aSPB[s] = __builtin_elementwise_fma(wv2, hSPB, aSPB[s]);
            }
        }

        // ---- emit output row oy = y0 + j - 10 from slot (P+1)%11 ----
        const int oy = y0 + j - 2 * RAD;
        if (j >= 2 * RAD && oy < IMG_H) {   // wave-uniform
            const int e2 = (P + 1) % KW;
            #pragma unroll
            for (int px = 0; px < 2; ++px) {
                const v2f mu = px ? aMuB[e2] : aMuA[e2];
                const v2f SP = px ? aSPB[e2] : aSPA[e2];
                const v2f musq = mu * mu;
                const float mu12  = mu.x * mu.y;
                const float musum = musq.x + musq.y;
                const float ssum  = SP.x - musum;          // sigma1^2+sigma2^2
                const float s12   = SP.y - mu12;           // sigma12
                const float num = fmaf(2.f, mu12, C1F) * fmaf(2.f, s12, C2F);
                const float den = (musum + C1F) * (ssum + C2F);
                acc = fmaf(num, __builtin_amdgcn_rcpf(den), acc);
            }
        }
    }

    // ---- block reduction, one atomic per block ----
    #pragma unroll
    for (int off = 32; off > 0; off >>= 1)
        acc += __shfl_xor(acc, off, 64);
    if (lane == 0) red[wvi] = acc;
    __syncthreads();
    if (tid == 0) {
        const float s = red[0] + red[1] + red[2] + red[3];
        atomicAdd(out, s * inv_n);
    }
}

extern "C" void kernel_launch(void* const* d_in, const int* in_sizes, int n_in,
                              void* d_out, int out_size, void* d_ws, size_t ws_size,
                              hipStream_t stream) {
    (void)in_sizes; (void)n_in; (void)d_ws; (void)ws_size;
    const float* img1 = (const float*)d_in[0];
    const float* img2 = (const float*)d_in[1];
    float* out = (float*)d_out;

    // d_out is re-poisoned to 0xAA before every launch; zero it (capture-safe).
    hipMemsetAsync(out, 0, (size_t)out_size * sizeof(float), stream);

    // Gaussian weights on host, double precision (same math as the original
    // device prologue); float-rounded -> identical weights.
    GaussW gw;
    {
        double t[KW];
        double s = 0.0;
        for (int i = 0; i < KW; ++i) {
            const double c = (double)(i - RAD);
            t[i] = exp(-(c * c) / 4.5);   // 2*sigma^2 = 4.5
            s += t[i];
        }
        for (int i = 0; i < KW; ++i) gw.g[i] = (float)(t[i] / s);
    }

    const float inv_n = 1.0f / (16.0f * 3.0f * 512.0f * 512.0f);
    // 32 y-tiles (16 rows each) x 48 planes; 4 waves = 4 col-strips.
    // 1536 blocks = EXACTLY 6 blocks/CU (balanced), 24 waves/CU resident.
    dim3 grid(32, 48, 1);
    ssim_fused_kernel<<<grid, dim3(256, 1, 1), 0, stream>>>(img1, img2, out, inv_n, gw);
}

// Round 5
// 160.296 us; speedup vs baseline: 1.4472x; 1.4472x over previous
//
#include <hip/hip_runtime.h>
#include <math.h>

// SSIM fused single pass, v10.
// History: v5 = 67.2us/disp, VALUBusy 52%, HBM 12%, 0 conflicts, VGPR 80.
//   v6 (pipelined staging) NEUTRAL: LDS/vmcnt roundtrip wasn't the stall.
//   v7 (TY=23, 1104 blocks) REGRESSED: 80 CUs carried 5 blocks vs 4 -> +27%.
//   v8 ABORTED: macro param shadowed caller's P -> self-init UB.
//   v9 (TY=16, FULL 26-phase unroll) REGRESSED 148us: VGPR 80 -> 148, only
//     3 waves/SIMD resident -> 6 blocks/CU ran as 2 sequential rounds of 3.
//     VALU-cycle accounting still closes (26% x 148us = the work) -> pure
//     stall; the occupancy hypothesis has never actually executed.
// v10 = TY=16 balanced-grid occupancy experiment WITH the register-pressure
// control v5/v7 proved:
//  * rolled outer loop (#pragma clang loop unroll(disable)) over NJB=2
//    11-phase groups (unrolled inner) -- the structure that codegen'd
//    VGPR=80 -- plus an explicit 4-phase tail j=22..25 (P=j%11=0..3
//    compile-time, 22=2*11).
//  * phase body in a macro with HYGIENIC names (mJ/mP/mPREF -> pj/pP);
//    no caller-name shadowing possible (v8's bug).
//  * grid (32,48) = 1536 blocks = EXACTLY 6 blocks/CU balanced; VGPR 80
//    => 6 waves/SIMD cap => all 24 waves/CU co-resident. 2x v5's hiding.
//  * GATING CHECK on the result: VGPR must be <= ~90, else void.

#define KW 11
#define RAD 5
#define IMG_W 512
#define IMG_H 512
#define TY 16                // output rows per tile; 26 phases = 2*11 + 4
#define NJB 2
#define NV4 70               // 140 staged (a,b) pairs = 70 v4f per row buffer
#define C1F 0.0001f          // 0.01^2
#define C2F 0.0009f          // 0.03^2

typedef float v2f __attribute__((ext_vector_type(2)));
typedef float v4f __attribute__((ext_vector_type(4)));

struct GaussW { float g[KW]; };

// One phase: stage row pj, prefetch row pj+1 (if mPREF), H-conv, V-scatter,
// emit. mP (== pj % 11) must const-fold; called only from unrolled contexts
// with literal mP. All interior names are pj/pP/p*-prefixed: they cannot
// shadow caller locals (jb, P, j are never used inside).
#define PHASE(mJ, mP, mPREF) do {                                              \
    const int pj = (mJ);                                                       \
    const int pP = (mP);                                                       \
    const int pbuf = pj & 1;                                                   \
    v4f* __restrict__ wrow = rows[wvi][pbuf];                                  \
    /* ---- stage row pj (regs -> wave-private LDS) ---- */                    \
    wrow[lane] = curm;                          /* ds_write_b128 */            \
    if (lane < 6) wrow[64 + lane] = curh;                                      \
    __threadfence_block();   /* wave-local lgkmcnt drain; W_pj < R_pj */       \
    /* ---- prefetch row pj+1 (latency covered by this iter's math) ---- */    \
    if (mPREF) load_row(pj + 1, curm, curh);                                   \
    /* ---- read the 14-pair window: v4f slots lane..lane+6 ---- */            \
    v4f e[7];                                                                  \
    _Pragma("unroll")                                                          \
    for (int r = 0; r < 7; ++r) e[r] = wrow[lane + r];   /* ds_read_b128 */    \
    v2f ab[14], sp[14];                                                        \
    _Pragma("unroll")                                                          \
    for (int i = 0; i < 14; ++i) {                                             \
        const v4f q = e[i >> 1];                                               \
        ab[i] = (i & 1) ? (v2f){q.z, q.w} : (v2f){q.x, q.y};                   \
    }                                                                          \
    _Pragma("unroll")                                                          \
    for (int i = 1; i <= 12; ++i) {                                            \
        const v2f t = ab[i];                                                   \
        sp[i] = (v2f){fmaf(t.x, t.x, t.y * t.y), t.x * t.y};                   \
    }                                                                          \
    /* ---- horizontal 11-tap conv, 2 px, packed ---- */                       \
    v2f hMuA = (v2f){0.f, 0.f}, hSPA = (v2f){0.f, 0.f};                        \
    v2f hMuB = (v2f){0.f, 0.f}, hSPB = (v2f){0.f, 0.f};                        \
    _Pragma("unroll")                                                          \
    for (int k = 0; k < KW; ++k) {                                             \
        const v2f gk = (v2f){g[k], g[k]};                                      \
        hMuA = __builtin_elementwise_fma(gk, ab[1 + k], hMuA);                 \
        hSPA = __builtin_elementwise_fma(gk, sp[1 + k], hSPA);                 \
        hMuB = __builtin_elementwise_fma(gk, ab[2 + k], hMuB);                 \
        hSPB = __builtin_elementwise_fma(gk, sp[2 + k], hSPB);                 \
    }                                                                          \
    /* ---- vertical scatter; slot s==pP gets its FIRST tap: assign ---- */    \
    _Pragma("unroll")                                                          \
    for (int s = 0; s < KW; ++s) {                                             \
        const float wt = g[(pP - s + KW) % KW];                                \
        const v2f wv2 = (v2f){wt, wt};                                         \
        if (s == pP) {                                                         \
            aMuA[s] = wv2 * hMuA;  aSPA[s] = wv2 * hSPA;                       \
            aMuB[s] = wv2 * hMuB;  aSPB[s] = wv2 * hSPB;                       \
        } else {                                                               \
            aMuA[s] = __builtin_elementwise_fma(wv2, hMuA, aMuA[s]);           \
            aSPA[s] = __builtin_elementwise_fma(wv2, hSPA, aSPA[s]);           \
            aMuB[s] = __builtin_elementwise_fma(wv2, hMuB, aMuB[s]);           \
            aSPB[s] = __builtin_elementwise_fma(wv2, hSPB, aSPB[s]);           \
        }                                                                      \
    }                                                                          \
    /* ---- emit output row oy = y0 + pj - 10 from slot (pP+1)%11 ---- */      \
    const int oy = y0 + pj - 2 * RAD;                                          \
    if (pj >= 2 * RAD && oy < IMG_H) {   /* wave-uniform */                    \
        const int e2 = (pP + 1) % KW;                                          \
        _Pragma("unroll")                                                      \
        for (int px = 0; px < 2; ++px) {                                       \
            const v2f mu = px ? aMuB[e2] : aMuA[e2];                           \
            const v2f SP = px ? aSPB[e2] : aSPA[e2];                           \
            const v2f musq = mu * mu;                                          \
            const float mu12  = mu.x * mu.y;                                   \
            const float musum = musq.x + musq.y;                               \
            const float ssum  = SP.x - musum;          /* sig1^2+sig2^2 */     \
            const float s12   = SP.y - mu12;           /* sigma12 */           \
            const float num = fmaf(2.f, mu12, C1F) * fmaf(2.f, s12, C2F);      \
            const float den = (musum + C1F) * (ssum + C2F);                    \
            acc = fmaf(num, __builtin_amdgcn_rcpf(den), acc);                  \
        }                                                                      \
    }                                                                          \
} while (0)

__global__ __launch_bounds__(256) void ssim_fused_kernel(
    const float* __restrict__ img1,
    const float* __restrict__ img2,
    float* __restrict__ out,
    float inv_n,
    GaussW gw)
{
    __shared__ v4f rows[4][2][NV4];   // [wave][double-buffer][v4f = 2 (a,b) pairs]
    __shared__ float red[4];

    const int tid  = threadIdx.x;
    const int lane = tid & 63;
    const int wvi  = tid >> 6;

    const int x0 = wvi * 128;              // wave's 128-col strip
    const int y0 = blockIdx.x * TY;        // wave's first output row

    const size_t pbase = (size_t)blockIdx.y * (size_t)(IMG_W * IMG_H);
    const float* __restrict__ p1 = img1 + pbase;
    const float* __restrict__ p2 = img2 + pbase;

    // Gaussian weights: by-value kernarg -> SGPRs (wave-uniform).
    float g[KW];
    #pragma unroll
    for (int i = 0; i < KW; ++i) g[i] = gw.g[i];

    // Staged entries cover cols x0-6 .. x0+133 (140 entries, even start for
    // aligned float2 loads). Lane t owns entries {2t, 2t+1}; lanes 0..5 also
    // stage halo entries {128+2l, 129+2l}.
    const int cm  = x0 - 6 + 2 * lane;                 // main col (even)
    const int cmc = min(max(cm, 0), IMG_W - 2);        // clamped, even
    const float mm0 = (cm     >= 0 && cm     < IMG_W) ? 1.f : 0.f;
    const float mm1 = (cm + 1 >= 0 && cm + 1 < IMG_W) ? 1.f : 0.f;
    const int ch  = x0 + 122 + 2 * lane;               // halo col (lanes 0..5)
    const int chc = min(max(ch, 0), IMG_W - 2);
    const float mh0 = (ch     < IMG_W) ? 1.f : 0.f;
    const float mh1 = (ch + 1 < IMG_W) ? 1.f : 0.f;

    // Load row (y0-RAD+j) into interleaved+masked (a0,b0,a1,b1) v4f regs.
    auto load_row = [&](int j, v4f& vm, v4f& vh) {
        const int ir = y0 - RAD + j;
        vm = (v4f){0.f, 0.f, 0.f, 0.f};
        vh = (v4f){0.f, 0.f, 0.f, 0.f};
        if ((unsigned)ir < (unsigned)IMG_H) {   // wave-uniform branch
            const float* r1 = p1 + ir * IMG_W;
            const float* r2 = p2 + ir * IMG_W;
            const v2f a = *reinterpret_cast<const v2f*>(r1 + cmc);
            const v2f b = *reinterpret_cast<const v2f*>(r2 + cmc);
            vm = (v4f){a.x * mm0, b.x * mm0, a.y * mm1, b.y * mm1};
            if (lane < 6) {
                const v2f ah = *reinterpret_cast<const v2f*>(r1 + chc);
                const v2f bh = *reinterpret_cast<const v2f*>(r2 + chc);
                vh = (v4f){ah.x * mh0, bh.x * mh0, ah.y * mh1, bh.y * mh1};
            }
        }
    };

    // V scatter accumulators for the thread's 2 columns (A=2lane, B=2lane+1):
    // slot s holds output row m with m%11==s.  (mu1,mu2) and (S,P) per px.
    v2f aMuA[KW], aSPA[KW], aMuB[KW], aSPB[KW];
    #pragma unroll
    for (int s = 0; s < KW; ++s) {
        aMuA[s] = (v2f){0.f, 0.f}; aSPA[s] = (v2f){0.f, 0.f};
        aMuB[s] = (v2f){0.f, 0.f}; aSPB[s] = (v2f){0.f, 0.f};
    }

    v4f curm, curh;
    load_row(0, curm, curh);

    float acc = 0.f;

    // ---- rolled outer loop: 2 full 11-phase groups (j = 0..21) ----
    // This rolled/unrolled split is what keeps VGPR at 80 (v5/v7-proven).
    #pragma clang loop unroll(disable)
    for (int jb = 0; jb < NJB; ++jb) {
        #pragma unroll
        for (int P = 0; P < KW; ++P) {
            PHASE(jb * KW + P, P, 1);
        }
    }
    // ---- 4-phase tail (j = 22..25, P = 0..3); last phase skips prefetch ----
    #pragma unroll
    for (int Pt = 0; Pt < 4; ++Pt) {
        PHASE(2 * KW + Pt, Pt, (Pt < 3));
    }

    // ---- block reduction, one atomic per block ----
    #pragma unroll
    for (int off = 32; off > 0; off >>= 1)
        acc += __shfl_xor(acc, off, 64);
    if (lane == 0) red[wvi] = acc;
    __syncthreads();
    if (tid == 0) {
        const float s = red[0] + red[1] + red[2] + red[3];
        atomicAdd(out, s * inv_n);
    }
}

extern "C" void kernel_launch(void* const* d_in, const int* in_sizes, int n_in,
                              void* d_out, int out_size, void* d_ws, size_t ws_size,
                              hipStream_t stream) {
    (void)in_sizes; (void)n_in; (void)d_ws; (void)ws_size;
    const float* img1 = (const float*)d_in[0];
    const float* img2 = (const float*)d_in[1];
    float* out = (float*)d_out;

    // d_out is re-poisoned to 0xAA before every launch; zero it (capture-safe).
    hipMemsetAsync(out, 0, (size_t)out_size * sizeof(float), stream);

    // Gaussian weights on host, double precision (same math as the original
    // device prologue); float-rounded -> identical weights.
    GaussW gw;
    {
        double t[KW];
        double s = 0.0;
        for (int i = 0; i < KW; ++i) {
            const double c = (double)(i - RAD);
            t[i] = exp(-(c * c) / 4.5);   // 2*sigma^2 = 4.5
            s += t[i];
        }
        for (int i = 0; i < KW; ++i) gw.g[i] = (float)(t[i] / s);
    }

    const float inv_n = 1.0f / (16.0f * 3.0f * 512.0f * 512.0f);
    // 32 y-tiles (16 rows each) x 48 planes; 4 waves = 4 col-strips.
    // 1536 blocks = EXACTLY 6 blocks/CU (balanced), 24 waves/CU resident.
    dim3 grid(32, 48, 1);
    ssim_fused_kernel<<<grid, dim3(256, 1, 1), 0, stream>>>(img1, img2, out, inv_n, gw);
}

// Round 6
// 155.545 us; speedup vs baseline: 1.4914x; 1.0305x over previous
//
#include <hip/hip_runtime.h>
#include <math.h>

// SSIM fused single pass, v11.
// History: v5 = 67.2us/disp (VALUBusy 52%, HBM 12%, VGPR 80, 0 conflicts).
//   v6 (no fence, pipelined staging)      NEUTRAL  -> LDS roundtrip not the stall.
//   v7 (TY=23, imbalanced grid)           REGRESS  -> straggler CUs, not a test.
//   v8 (macro self-init UB)               ABORT.
//   v9 (full 26-phase unroll, ~70KB body) REGRESS 148us even at HIGHER occupancy.
//   v10 (balanced 6 blk/CU, VGPR 80 OK)   REGRESS 107us, VALUBusy FELL to 37%:
//        adding waves REDUCED per-CU throughput -> congesting shared resource.
// Unifying theory: L1I thrash. The 11-phase unrolled body is ~35KB > 32KB L1I;
// every outer iteration refetches it from L2. Explains v5's ~3000cy/phase
// per-wave stall (not data latency - v6 disproved that), v9's collapse
// (~70KB body), and v10's negative scaling (more waves at different phases
// thrash harder).
// v11: ROLL the phase loop; kill the %11 indexing that forced the unroll.
// Value-rotating accumulators with the shift FUSED into the scatter FMA:
//   slot t = "output completing in t more phases" (10 live slots):
//     emit      = fma(g[10], h, acc[0])            (only when j>=10)
//     acc[t]    = fma(g[9-t], h, acc[t+1]) t=0..8  (shift+tap in one FMA)
//     acc[9]    = g[0]*h                           (birth, assign)
//   Same 11 taps in the same order as v5 -> bit-identical math, ZERO extra
//   ops, -1 live slot. Body ~3.5KB -> I$ resident. Everything else = v5:
//   TY=34, grid (16,48)=768=3 blocks/CU balanced, staging+fence+prefetch,
//   host-computed weights (validated absmax 0.0 in v7/v10).

#define KW 11
#define RAD 5
#define IMG_W 512
#define IMG_H 512
#define TY 34                // output rows per wave tile; 44 phases
#define NPH (TY + 2 * RAD)   // 44
#define NV4 70               // 140 staged (a,b) pairs = 70 v4f per row buffer
#define C1F 0.0001f          // 0.01^2
#define C2F 0.0009f          // 0.03^2

typedef float v2f __attribute__((ext_vector_type(2)));
typedef float v4f __attribute__((ext_vector_type(4)));

struct GaussW { float g[KW]; };

__global__ __launch_bounds__(256) void ssim_fused_kernel(
    const float* __restrict__ img1,
    const float* __restrict__ img2,
    float* __restrict__ out,
    float inv_n,
    GaussW gw)
{
    __shared__ v4f rows[4][2][NV4];   // [wave][double-buffer][v4f = 2 (a,b) pairs]
    __shared__ float red[4];

    const int tid  = threadIdx.x;
    const int lane = tid & 63;
    const int wvi  = tid >> 6;

    const int x0 = wvi * 128;              // wave's 128-col strip
    const int y0 = blockIdx.x * TY;        // wave's first output row

    const size_t pbase = (size_t)blockIdx.y * (size_t)(IMG_W * IMG_H);
    const float* __restrict__ p1 = img1 + pbase;
    const float* __restrict__ p2 = img2 + pbase;

    // Gaussian weights: by-value kernarg -> SGPRs (wave-uniform).
    float g[KW];
    #pragma unroll
    for (int i = 0; i < KW; ++i) g[i] = gw.g[i];

    // Staged entries cover cols x0-6 .. x0+133 (140 entries, even start for
    // aligned float2 loads). Lane t owns entries {2t, 2t+1}; lanes 0..5 also
    // stage halo entries {128+2l, 129+2l}.
    const int cm  = x0 - 6 + 2 * lane;                 // main col (even)
    const int cmc = min(max(cm, 0), IMG_W - 2);        // clamped, even
    const float mm0 = (cm     >= 0 && cm     < IMG_W) ? 1.f : 0.f;
    const float mm1 = (cm + 1 >= 0 && cm + 1 < IMG_W) ? 1.f : 0.f;
    const int ch  = x0 + 122 + 2 * lane;               // halo col (lanes 0..5)
    const int chc = min(max(ch, 0), IMG_W - 2);
    const float mh0 = (ch     < IMG_W) ? 1.f : 0.f;
    const float mh1 = (ch + 1 < IMG_W) ? 1.f : 0.f;

    // Load row (y0-RAD+j) into interleaved+masked (a0,b0,a1,b1) v4f regs.
    auto load_row = [&](int j, v4f& vm, v4f& vh) {
        const int ir = y0 - RAD + j;
        vm = (v4f){0.f, 0.f, 0.f, 0.f};
        vh = (v4f){0.f, 0.f, 0.f, 0.f};
        if ((unsigned)ir < (unsigned)IMG_H) {   // wave-uniform branch
            const float* r1 = p1 + ir * IMG_W;
            const float* r2 = p2 + ir * IMG_W;
            const v2f a = *reinterpret_cast<const v2f*>(r1 + cmc);
            const v2f b = *reinterpret_cast<const v2f*>(r2 + cmc);
            vm = (v4f){a.x * mm0, b.x * mm0, a.y * mm1, b.y * mm1};
            if (lane < 6) {
                const v2f ah = *reinterpret_cast<const v2f*>(r1 + chc);
                const v2f bh = *reinterpret_cast<const v2f*>(r2 + chc);
                vh = (v4f){ah.x * mh0, bh.x * mh0, ah.y * mh1, bh.y * mh1};
            }
        }
    };

    // Value-rotating V accumulators: slot t completes in t more phases.
    // (mu1,mu2) and (S,P) per px for the thread's 2 columns A=2lane, B=2lane+1.
    // 10 live slots (the 11th tap is applied at emit). Zero-init for hygiene
    // (slots emitted at j>=10 are always fully born; init kills stale NaNs).
    v2f aMuA[KW - 1], aSPA[KW - 1], aMuB[KW - 1], aSPB[KW - 1];
    #pragma unroll
    for (int t = 0; t < KW - 1; ++t) {
        aMuA[t] = (v2f){0.f, 0.f}; aSPA[t] = (v2f){0.f, 0.f};
        aMuB[t] = (v2f){0.f, 0.f}; aSPB[t] = (v2f){0.f, 0.f};
    }

    v4f curm, curh;
    load_row(0, curm, curh);

    float acc = 0.f;

    // ROLLED phase loop: body ~3.5KB, I$ resident. All register-array
    // indices inside are compile-time (unrolled inner loops only).
    #pragma clang loop unroll(disable)
    for (int j = 0; j < NPH; ++j) {
        v4f* __restrict__ wrow = rows[wvi][j & 1];

        // ---- stage row j (regs -> wave-private LDS) ----
        wrow[lane] = curm;                          // ds_write_b128
        if (lane < 6) wrow[64 + lane] = curh;
        __threadfence_block();   // wave-local lgkmcnt drain; orders W_j < R_j

        // ---- prefetch row j+1 (latency covered by this iter's math) ----
        if (j < NPH - 1) load_row(j + 1, curm, curh);

        // ---- read the 14-pair window: v4f slots lane..lane+6 ----
        v4f e[7];
        #pragma unroll
        for (int r = 0; r < 7; ++r) e[r] = wrow[lane + r];   // ds_read_b128

        // pairs: idx 0..13; pair(i) = i even ? e[i/2].xy : e[i/2].zw
        // window for col A uses pairs 1..11, col B uses pairs 2..12.
        v2f ab[14], sp[14];
        #pragma unroll
        for (int i = 0; i < 14; ++i) {
            const v4f q = e[i >> 1];
            ab[i] = (i & 1) ? (v2f){q.z, q.w} : (v2f){q.x, q.y};
        }
        #pragma unroll
        for (int i = 1; i <= 12; ++i) {
            const v2f t = ab[i];
            sp[i] = (v2f){fmaf(t.x, t.x, t.y * t.y), t.x * t.y};
        }

        // ---- horizontal 11-tap conv, 2 px, packed ----
        v2f hMuA = (v2f){0.f, 0.f}, hSPA = (v2f){0.f, 0.f};
        v2f hMuB = (v2f){0.f, 0.f}, hSPB = (v2f){0.f, 0.f};
        #pragma unroll
        for (int k = 0; k < KW; ++k) {
            const v2f gk = (v2f){g[k], g[k]};
            hMuA = __builtin_elementwise_fma(gk, ab[1 + k], hMuA);
            hSPA = __builtin_elementwise_fma(gk, sp[1 + k], hSPA);
            hMuB = __builtin_elementwise_fma(gk, ab[2 + k], hMuB);
            hSPB = __builtin_elementwise_fma(gk, sp[2 + k], hSPB);
        }

        // ---- emit output row oy = y0 + j - 10: last tap g[10] applied
        //      directly against acc[0] (read BEFORE the fused shift) ----
        const int oy = y0 + j - 2 * RAD;
        if (j >= 2 * RAD && oy < IMG_H) {   // wave-uniform
            const v2f g10 = (v2f){g[KW - 1], g[KW - 1]};
            #pragma unroll
            for (int px = 0; px < 2; ++px) {
                const v2f mu = __builtin_elementwise_fma(
                    g10, px ? hMuB : hMuA, px ? aMuB[0] : aMuA[0]);
                const v2f SP = __builtin_elementwise_fma(
                    g10, px ? hSPB : hSPA, px ? aSPB[0] : aSPA[0]);
                const v2f musq = mu * mu;
                const float mu12  = mu.x * mu.y;
                const float musum = musq.x + musq.y;
                const float ssum  = SP.x - musum;          // sigma1^2+sigma2^2
                const float s12   = SP.y - mu12;           // sigma12
                const float num = fmaf(2.f, mu12, C1F) * fmaf(2.f, s12, C2F);
                const float den = (musum + C1F) * (ssum + C2F);
                acc = fmaf(num, __builtin_amdgcn_rcpf(den), acc);
            }
        }

        // ---- fused shift+scatter (ascending t reads old acc[t+1]):
        //      slot t gets tap g[9-t]; same tap order per output as v5 ----
        #pragma unroll
        for (int t = 0; t < KW - 2; ++t) {   // t = 0..8
            const v2f w = (v2f){g[KW - 2 - t], g[KW - 2 - t]};   // g[9-t]
            aMuA[t] = __builtin_elementwise_fma(w, hMuA, aMuA[t + 1]);
            aSPA[t] = __builtin_elementwise_fma(w, hSPA, aSPA[t + 1]);
            aMuB[t] = __builtin_elementwise_fma(w, hMuB, aMuB[t + 1]);
            aSPB[t] = __builtin_elementwise_fma(w, hSPB, aSPB[t + 1]);
        }
        {   // birth: newest slot, first tap g[0] (assign)
            const v2f g0 = (v2f){g[0], g[0]};
            aMuA[KW - 2] = g0 * hMuA;  aSPA[KW - 2] = g0 * hSPA;
            aMuB[KW - 2] = g0 * hMuB;  aSPB[KW - 2] = g0 * hSPB;
        }
    }

    // ---- block reduction, one atomic per block ----
    #pragma unroll
    for (int off = 32; off > 0; off >>= 1)
        acc += __shfl_xor(acc, off, 64);
    if (lane == 0) red[wvi] = acc;
    __syncthreads();
    if (tid == 0) {
        const float s = red[0] + red[1] + red[2] + red[3];
        atomicAdd(out, s * inv_n);
    }
}

extern "C" void kernel_launch(void* const* d_in, const int* in_sizes, int n_in,
                              void* d_out, int out_size, void* d_ws, size_t ws_size,
                              hipStream_t stream) {
    (void)in_sizes; (void)n_in; (void)d_ws; (void)ws_size;
    const float* img1 = (const float*)d_in[0];
    const float* img2 = (const float*)d_in[1];
    float* out = (float*)d_out;

    // d_out is re-poisoned to 0xAA before every launch; zero it (capture-safe).
    hipMemsetAsync(out, 0, (size_t)out_size * sizeof(float), stream);

    // Gaussian weights on host, double precision (same math as the original
    // device prologue); float-rounded -> identical weights (absmax 0.0 in
    // v7/v10 benches).
    GaussW gw;
    {
        double t[KW];
        double s = 0.0;
        for (int i = 0; i < KW; ++i) {
            const double c = (double)(i - RAD);
            t[i] = exp(-(c * c) / 4.5);   // 2*sigma^2 = 4.5
            s += t[i];
        }
        for (int i = 0; i < KW; ++i) gw.g[i] = (float)(t[i] / s);
    }

    const float inv_n = 1.0f / (16.0f * 3.0f * 512.0f * 512.0f);
    // 16 y-tiles (34 rows, tail masked) x 48 planes; 4 waves = 4 col-strips.
    dim3 grid(16, 48, 1);   // 768 blocks = exactly 3 blocks/CU (v5-proven)
    ssim_fused_kernel<<<grid, dim3(256, 1, 1), 0, stream>>>(img1, img2, out, inv_n, gw);
}